// Round 1
// baseline (287.839 us; speedup 1.0000x reference)
//
#include <hip/hip_runtime.h>

// OWA pooling: 3x3 window, stride 2, pad bottom/right by 1 (zeros),
// sort 9 window values descending per channel, weighted sum with kernel[9][64].
//
// Input : (16, 224, 224, 64) fp32, NHWC
// Kernel: (9, 64) fp32
// Output: (16, 112, 112, 64) fp32

#define BB 16
#define HH 224
#define WW 224
#define CC 64
#define PH 112
#define PW 112

__device__ __forceinline__ void ce(float4& a, float4& b) {
    float4 lo, hi;
    lo.x = fminf(a.x, b.x); hi.x = fmaxf(a.x, b.x);
    lo.y = fminf(a.y, b.y); hi.y = fmaxf(a.y, b.y);
    lo.z = fminf(a.z, b.z); hi.z = fmaxf(a.z, b.z);
    lo.w = fminf(a.w, b.w); hi.w = fmaxf(a.w, b.w);
    a = lo; b = hi;
}

__global__ __launch_bounds__(256) void owa_pool_kernel(
    const float* __restrict__ in, const float* __restrict__ kw,
    float* __restrict__ out) {
    // one thread = one output pixel x 4 channels (float4)
    int idx = blockIdx.x * blockDim.x + threadIdx.x;
    // total threads = BB*PH*PW*16
    int cg  = idx & 15;          // channel group (4 channels)
    int pix = idx >> 4;
    int ow  = pix % PW;
    int t   = pix / PW;
    int oh  = t % PH;
    int b   = t / PH;

    int c0 = cg * 4;

    // per-channel weights: kw[k*64 + c0..c0+3]
    float4 wgt[9];
#pragma unroll
    for (int k = 0; k < 9; ++k)
        wgt[k] = *reinterpret_cast<const float4*>(kw + k * CC + c0);

    // gather 3x3 window (k = kh*3+kw), zero for out-of-bounds (pad bottom/right)
    float4 v[9];
    int ih0 = oh * 2, iw0 = ow * 2;
#pragma unroll
    for (int kh = 0; kh < 3; ++kh) {
        int ih = ih0 + kh;
#pragma unroll
        for (int kwi = 0; kwi < 3; ++kwi) {
            int iw = iw0 + kwi;
            float4 val = make_float4(0.f, 0.f, 0.f, 0.f);
            if (ih < HH && iw < WW) {
                long off = (((long)b * HH + ih) * WW + iw) * CC + c0;
                val = *reinterpret_cast<const float4*>(in + off);
            }
            v[kh * 3 + kwi] = val;
        }
    }

    // sort ascending with the optimal 25-CE network for n=9
    ce(v[0], v[3]); ce(v[1], v[7]); ce(v[2], v[5]); ce(v[4], v[8]);
    ce(v[0], v[7]); ce(v[2], v[4]); ce(v[3], v[8]); ce(v[5], v[6]);
    ce(v[0], v[2]); ce(v[1], v[3]); ce(v[4], v[5]); ce(v[7], v[8]);
    ce(v[1], v[4]); ce(v[3], v[6]); ce(v[5], v[7]);
    ce(v[0], v[1]); ce(v[2], v[4]); ce(v[3], v[5]); ce(v[6], v[8]);
    ce(v[2], v[3]); ce(v[4], v[5]); ce(v[6], v[7]);
    ce(v[1], v[2]); ce(v[3], v[4]); ce(v[5], v[6]);

    // descending rank k pairs ascending index 8-k
    float4 acc = make_float4(0.f, 0.f, 0.f, 0.f);
#pragma unroll
    for (int k = 0; k < 9; ++k) {
        float4 wk = wgt[8 - k];
        acc.x += v[k].x * wk.x;
        acc.y += v[k].y * wk.y;
        acc.z += v[k].z * wk.z;
        acc.w += v[k].w * wk.w;
    }

    long oidx = (((long)b * PH + oh) * PW + ow) * CC + c0;
    *reinterpret_cast<float4*>(out + oidx) = acc;
}

extern "C" void kernel_launch(void* const* d_in, const int* in_sizes, int n_in,
                              void* d_out, int out_size, void* d_ws, size_t ws_size,
                              hipStream_t stream) {
    const float* in = (const float*)d_in[0];
    const float* kw = (const float*)d_in[1];
    float* out = (float*)d_out;

    const int total_threads = BB * PH * PW * 16;  // 3,211,264
    const int block = 256;
    const int grid = (total_threads + block - 1) / block;  // 12,544
    owa_pool_kernel<<<grid, block, 0, stream>>>(in, kw, out);
}